// Round 10
// baseline (102.889 us; speedup 1.0000x reference)
//
#include <hip/hip_runtime.h>

#define Bsz 4
#define Cch 64
#define Hh 128
#define Ww 128
#define NOFF 18      // 2*3*3 offset channels
#define CK 576       // 64*9 reduction length for deform einsum (K = k*64 + c)
#define CKPAD 580    // smp row stride (bf16): 1160B -> conflict-free r/w patterns

typedef __attribute__((ext_vector_type(8))) short short8;
typedef __attribute__((ext_vector_type(4))) float floatx4;

__device__ __forceinline__ unsigned short f2bf(float f) {
    union { float f; unsigned u; } v; v.f = f;
    unsigned r = v.u + 0x7fff + ((v.u >> 16) & 1);   // round-to-nearest-even
    return (unsigned short)(r >> 16);
}
__device__ __forceinline__ float bflo(unsigned d) {
    union { unsigned u; float f; } v; v.u = d << 16; return v.f;
}
__device__ __forceinline__ float bfhi(unsigned d) {
    union { unsigned u; float f; } v; v.u = d & 0xffff0000u; return v.f;
}

// ---------------------------------------------------------------------------
// Prep kernel.
//   blocks 0..1023   : transpose x||ref (NCHW f32) -> xtrc[b][h*w][128] bf16
//   blocks 1024..1167: deform weight w[oc][c][tap] -> wbf[oc][tap*64+c] bf16
//   blocks 1168..1311: offset weight wo[oc][ci][tap] -> w9[tap][32ocp][128ci] bf16
__global__ __launch_bounds__(256) void prep(const float* __restrict__ x,
                                            const float* __restrict__ ref,
                                            const float* __restrict__ wo,
                                            const float* __restrict__ w,
                                            unsigned short* __restrict__ xtrc,
                                            unsigned short* __restrict__ w9,
                                            unsigned short* __restrict__ wbf) {
    __shared__ unsigned tile[64][66];   // [cpair][px], +2 pad
    int bid = blockIdx.x;
    int tid = threadIdx.x;
    if (bid < 1024) {
        int b = bid >> 8;
        int hw0 = (bid & 255) << 6;
        int px = tid & 63, cg = tid >> 6;
        const float* xb = x + ((size_t)b << 20) + hw0 + px;
        const float* rb = ref + ((size_t)b << 20) + hw0 + px;
#pragma unroll
        for (int i = 0; i < 16; ++i) {
            int cpair = cg * 16 + i;        // c = 2*cpair, 2*cpair+1
            int c0 = cpair << 1;
            const float* s = (c0 < 64) ? xb : rb;
            int cl = c0 & 63;
            float v0 = s[(size_t)cl << 14];
            float v1 = s[(size_t)(cl + 1) << 14];
            tile[cpair][px] = (unsigned)f2bf(v0) | ((unsigned)f2bf(v1) << 16);
        }
        __syncthreads();
        int p2 = tid >> 4, cq = tid & 15;
#pragma unroll
        for (int j = 0; j < 4; ++j) {
            int px2 = (j << 4) + p2;
            unsigned short* orow = xtrc + (((size_t)(b << 14) + hw0 + px2) << 7);
#pragma unroll
            for (int jj = 0; jj < 2; ++jj) {
                unsigned v0 = tile[(cq << 1) + (jj << 5)][px2];
                unsigned v1 = tile[(cq << 1) + 1 + (jj << 5)][px2];
                *(uint2*)(orow + (cq << 2) + (jj << 6)) = make_uint2(v0, v1);
            }
        }
    } else if (bid < 1168) {
        int t = (bid - 1024) * 256 + tid;
        if (t < Cch * CK) {
            int oc = t / CK;
            int rem = t % CK;
            int k = rem >> 6, c = rem & 63;
            wbf[t] = f2bf(w[(oc * Cch + c) * 9 + k]);
        }
    } else {
        int t = (bid - 1168) * 256 + tid;
        if (t < 9 * 32 * 128) {
            int ci = t & 127, ocp = (t >> 7) & 31, tap = t >> 12;
            w9[t] = (ocp < NOFF) ? f2bf(wo[(ocp * 128 + ci) * 9 + tap]) : (unsigned short)0;
        }
    }
}

// ---------------------------------------------------------------------------
// Fused kernel, 8-wave version (32 waves/CU). Block = (b, h, 16-px strip).
// A0: stage tile3 from xtrc (coalesced, XOR-swizzled).
// A1: offset MFMA; 8 waves = 2 oc-tiles x 2 ci-halves x 2 tap-halves -> red.
// FIN: 2 waves reduce 4 partials -> bias+clip -> offsL (LDS only).
// B : bilinear gather; 512 threads = (px, c-quad, tap-half) -> smp.
// B1: deform MFMA; 8 waves = 4 o-tiles x 2 K-halves -> red -> store.
__global__ __launch_bounds__(512, 8) void fused_align(
        const unsigned short* __restrict__ xtrc,
        const unsigned short* __restrict__ w9,
        const unsigned short* __restrict__ wbf,
        const float* __restrict__ bias,
        float* __restrict__ out) {
    __shared__ union {
        unsigned short tile3[54 * 128];             // 13.5 KB
        unsigned short smp[16][CKPAD];              // 18.6 KB
    } u;
    __shared__ float red[8][64][4];                 // 8 KB
    __shared__ float offsL[16][20];                 // 1.3 KB

    int bi = blockIdx.x;
    int b = bi >> 10;
    int rem = bi & 1023;
    int h = rem >> 3;
    int w0 = (rem & 7) << 4;
    int tid = threadIdx.x;
    int wv = tid >> 6, lane = tid & 63;
    int r16 = lane & 15;
    int g = lane >> 4;

    const unsigned short* xrow = xtrc + ((size_t)b << 21);   // b * 16384 * 128

    // ---- Phase A0: stage 54 positions x 256B, fully coalesced ----
#pragma unroll
    for (int it = 0; it < 4; ++it) {
        int idx = it * 512 + tid;
        if (idx < 1728) {
            int lane32 = idx & 31;
            int pos = idx >> 5;              // row*18 + xx
            int row = pos / 18, xx = pos % 18;
            int yy = h + row - 1, xg = w0 + xx - 1;
            uint2 v = make_uint2(0u, 0u);
            if ((unsigned)yy < (unsigned)Hh && (unsigned)xg < (unsigned)Ww)
                v = *(const uint2*)(xrow + ((((yy << 7) + xg) << 7) + (lane32 << 2)));
            int ci0 = lane32 << 2;
            *(uint2*)(&u.tile3[(pos << 7) + (ci0 ^ ((xx & 7) << 3))]) = v;
        }
    }
    __syncthreads();

    // ---- Phase A1: offset conv MFMA; wv = to + 2*kh + 4*th ----
    {
        int to = wv & 1, kh = (wv >> 1) & 1, th = wv >> 2;
        floatx4 acc = {0.f, 0.f, 0.f, 0.f};
#define A1_TAP(tap)                                                                   \
        {                                                                             \
            int dy = (tap) / 3, dx = (tap) % 3;                                       \
            int xxr = r16 + dx;                                                       \
            const unsigned short* brow = &u.tile3[(dy * 18 + xxr) << 7];              \
            int sw = (xxr & 7) << 3;                                                  \
            const unsigned short* arow =                                              \
                w9 + ((size_t)((tap) * 32 + to * 16 + r16) << 7) + kh * 64;           \
            _Pragma("unroll")                                                         \
            for (int kk = 0; kk < 2; ++kk) {                                          \
                int cb = kh * 64 + kk * 32 + g * 8;                                   \
                short8 bb = *(const short8*)(brow + (cb ^ sw));                       \
                short8 a = *(const short8*)(arow + kk * 32 + g * 8);                  \
                acc = __builtin_amdgcn_mfma_f32_16x16x32_bf16(a, bb, acc, 0, 0, 0);   \
            }                                                                         \
        }
        if (th == 0) {
#pragma unroll
            for (int tap = 0; tap < 4; ++tap) A1_TAP(tap)
        } else {
#pragma unroll
            for (int tap = 4; tap < 9; ++tap) A1_TAP(tap)
        }
#undef A1_TAP
#pragma unroll
        for (int r = 0; r < 4; ++r) red[wv][lane][r] = acc[r];
    }
    __syncthreads();

    // ---- FIN: 2 waves fold 4 partials, bias+clip -> offsL ----
    if (wv < 2) {
        int to = wv;
#pragma unroll
        for (int r = 0; r < 4; ++r) {
            int oc = to * 16 + g * 4 + r;
            if (oc < NOFF) {
                float v = red[to][lane][r] + red[to + 2][lane][r]
                        + red[to + 4][lane][r] + red[to + 6][lane][r] + bias[oc];
                v = fminf(fmaxf(v, -10.0f), 10.0f);
                offsL[r16][oc] = v;
            }
        }
    }
    __syncthreads();   // offsL ready; tile3 dead -> smp may overwrite

    // ---- Phase B: bilinear gather; thread = (px, c-quad, tap-half) ----
    {
        int p = (tid >> 4) & 15;
        int cq = tid & 15;
        int hf = tid >> 8;
        const unsigned short* xb = xrow + (cq << 2);
#define B_TAP(k)                                                                      \
        {                                                                             \
            int ky = (k) / 3, kx = (k) % 3;                                           \
            float2 o = *(const float2*)(&offsL[p][2 * (k)]);                          \
            float ys = (float)(h - 1 + ky) + o.x;                                     \
            float xs = (float)(w0 + p - 1 + kx) + o.y;                                \
            float fy = floorf(ys), fx = floorf(xs);                                   \
            int iy0 = (int)fy, ix0 = (int)fx;                                         \
            float ty = ys - fy, tx = xs - fx;                                         \
            float wy0 = (1.f - ty) * (((unsigned)iy0 < (unsigned)Hh) ? 1.f : 0.f);    \
            float wy1 = ty * (((unsigned)(iy0 + 1) < (unsigned)Hh) ? 1.f : 0.f);      \
            float wx0 = (1.f - tx) * (((unsigned)ix0 < (unsigned)Ww) ? 1.f : 0.f);    \
            float wx1 = tx * (((unsigned)(ix0 + 1) < (unsigned)Ww) ? 1.f : 0.f);      \
            int ixb  = min(max(ix0, 0), Ww - 2);                                      \
            int iy0c = min(max(iy0, 0), Hh - 1);                                      \
            int iy1c = min(max(iy0 + 1, 0), Hh - 1);                                  \
            bool sw0 = (min(max(ix0, 0), Ww - 1) != ixb);                             \
            bool sw1 = (min(max(ix0 + 1, 0), Ww - 1) != ixb);                         \
            float w00 = wy0 * wx0, w01 = wy0 * wx1, w10 = wy1 * wx0, w11 = wy1 * wx1; \
            float A  = (sw0 ? 0.f : w00) + (sw1 ? 0.f : w01);                         \
            float Bw = (sw0 ? w00 : 0.f) + (sw1 ? w01 : 0.f);                         \
            float Cw = (sw0 ? 0.f : w10) + (sw1 ? 0.f : w11);                         \
            float Dw = (sw0 ? w10 : 0.f) + (sw1 ? w11 : 0.f);                         \
            int m0 = ((iy0c << 7) + ixb) << 7;                                        \
            int m1 = ((iy1c << 7) + ixb) << 7;                                        \
            uint2 q00 = *(const uint2*)(xb + m0);                                     \
            uint2 q01 = *(const uint2*)(xb + m0 + 128);                               \
            uint2 q10 = *(const uint2*)(xb + m1);                                     \
            uint2 q11 = *(const uint2*)(xb + m1 + 128);                               \
            float s0 = bflo(q00.x) * A + bflo(q01.x) * Bw                             \
                     + bflo(q10.x) * Cw + bflo(q11.x) * Dw;                           \
            float s1 = bfhi(q00.x) * A + bfhi(q01.x) * Bw                             \
                     + bfhi(q10.x) * Cw + bfhi(q11.x) * Dw;                           \
            float s2 = bflo(q00.y) * A + bflo(q01.y) * Bw                             \
                     + bflo(q10.y) * Cw + bflo(q11.y) * Dw;                           \
            float s3 = bfhi(q00.y) * A + bfhi(q01.y) * Bw                             \
                     + bfhi(q10.y) * Cw + bfhi(q11.y) * Dw;                           \
            *(uint2*)(&u.smp[p][(k) * 64 + cq * 4]) = make_uint2(                     \
                (unsigned)f2bf(s0) | ((unsigned)f2bf(s1) << 16),                      \
                (unsigned)f2bf(s2) | ((unsigned)f2bf(s3) << 16));                     \
        }
        if (hf == 0) {
#pragma unroll
            for (int k = 0; k < 4; ++k) B_TAP(k)
        } else {
#pragma unroll
            for (int k = 4; k < 9; ++k) B_TAP(k)
        }
#undef B_TAP
    }
    __syncthreads();

    // ---- Phase B1: deform MFMA; wv = to2 + 4*kkh ----
    {
        int to2 = wv & 3, kkh = wv >> 2;
        floatx4 acc2 = {0.f, 0.f, 0.f, 0.f};
        const short8* ap = (const short8*)(wbf + (size_t)(to2 * 16 + r16) * CK + g * 8);
        const unsigned short* bbase = &u.smp[r16][g * 8];
#pragma unroll
        for (int j = 0; j < 9; ++j) {
            int kk = kkh * 9 + j;
            short8 a = ap[kk * 4];
            short8 bb = *(const short8*)(bbase + kk * 32);
            acc2 = __builtin_amdgcn_mfma_f32_16x16x32_bf16(a, bb, acc2, 0, 0, 0);
        }
        if (kkh == 1) {
#pragma unroll
            for (int r = 0; r < 4; ++r) red[to2][lane][r] = acc2[r];
        }
        __syncthreads();
        if (kkh == 0) {
            size_t obase = ((size_t)(b * Cch + to2 * 16 + g * 4)) << 14;
            int hw = (h << 7) + w0 + r16;
#pragma unroll
            for (int r = 0; r < 4; ++r)
                out[obase + ((size_t)r << 14) + hw] = acc2[r] + red[to2][lane][r];
        }
    }
}

// ---------------------------------------------------------------------------
extern "C" void kernel_launch(void* const* d_in, const int* in_sizes, int n_in,
                              void* d_out, int out_size, void* d_ws, size_t ws_size,
                              hipStream_t stream) {
    const float* x      = (const float*)d_in[0];
    const float* ref    = (const float*)d_in[1];
    const float* wo     = (const float*)d_in[2];
    const float* bias   = (const float*)d_in[3];
    const float* weight = (const float*)d_in[4];
    float* out = (float*)d_out;

    unsigned short* w9   = (unsigned short*)d_ws;                      // 72 KB
    unsigned short* wbf  = (unsigned short*)((char*)d_ws + 131072);    // 72 KB
    unsigned short* xtrc = (unsigned short*)((char*)d_ws + 262144);    // 16.78 MB

    hipLaunchKernelGGL(prep, dim3(1312), dim3(256), 0, stream,
                       x, ref, wo, weight, xtrc, w9, wbf);
    hipLaunchKernelGGL(fused_align, dim3(Bsz * Hh * (Ww / 16)), dim3(512), 0, stream,
                       xtrc, w9, wbf, bias, out);
}

// Round 11
// 100.370 us; speedup vs baseline: 1.0251x; 1.0251x over previous
//
#include <hip/hip_runtime.h>

#define Bsz 4
#define Cch 64
#define Hh 128
#define Ww 128
#define NOFF 18      // 2*3*3 offset channels
#define CK 576       // 64*9 reduction length for deform einsum (K = k*64 + c)
#define CKPAD 580    // smp row stride (bf16): 1160B

typedef __attribute__((ext_vector_type(8))) short short8;
typedef __attribute__((ext_vector_type(4))) float floatx4;

__device__ __forceinline__ unsigned short f2bf(float f) {
    union { float f; unsigned u; } v; v.f = f;
    unsigned r = v.u + 0x7fff + ((v.u >> 16) & 1);   // round-to-nearest-even
    return (unsigned short)(r >> 16);
}
__device__ __forceinline__ float bflo(unsigned d) {
    union { unsigned u; float f; } v; v.u = d << 16; return v.f;
}
__device__ __forceinline__ float bfhi(unsigned d) {
    union { unsigned u; float f; } v; v.u = d & 0xffff0000u; return v.f;
}
__device__ __forceinline__ unsigned cvtpk(float lo, float hi) {   // {bf16(lo), bf16(hi)<<16}
    unsigned r;
    asm("v_cvt_pk_bf16_f32 %0, %1, %2" : "=v"(r) : "v"(lo), "v"(hi));
    return r;
}

// ---------------------------------------------------------------------------
// Prep kernel.
//   blocks 0..1023   : transpose x||ref (NCHW f32) -> xtrc[b][h*w][128] bf16
//   blocks 1024..1167: deform weight w[oc][c][tap] -> wbf[oc][tap*64+c] bf16
//   blocks 1168..1311: offset weight wo[oc][ci][tap] -> w9[tap][32ocp][128ci] bf16
__global__ __launch_bounds__(256) void prep(const float* __restrict__ x,
                                            const float* __restrict__ ref,
                                            const float* __restrict__ wo,
                                            const float* __restrict__ w,
                                            unsigned short* __restrict__ xtrc,
                                            unsigned short* __restrict__ w9,
                                            unsigned short* __restrict__ wbf) {
    __shared__ unsigned tile[64][66];   // [cpair][px], +2 pad
    int bid = blockIdx.x;
    int tid = threadIdx.x;
    if (bid < 1024) {
        int b = bid >> 8;
        int hw0 = (bid & 255) << 6;
        int px = tid & 63, cg = tid >> 6;
        const float* xb = x + ((size_t)b << 20) + hw0 + px;
        const float* rb = ref + ((size_t)b << 20) + hw0 + px;
#pragma unroll
        for (int i = 0; i < 16; ++i) {
            int cpair = cg * 16 + i;        // c = 2*cpair, 2*cpair+1
            int c0 = cpair << 1;
            const float* s = (c0 < 64) ? xb : rb;
            int cl = c0 & 63;
            float v0 = s[(size_t)cl << 14];
            float v1 = s[(size_t)(cl + 1) << 14];
            tile[cpair][px] = (unsigned)f2bf(v0) | ((unsigned)f2bf(v1) << 16);
        }
        __syncthreads();
        int p2 = tid >> 4, cq = tid & 15;
#pragma unroll
        for (int j = 0; j < 4; ++j) {
            int px2 = (j << 4) + p2;
            unsigned short* orow = xtrc + (((size_t)(b << 14) + hw0 + px2) << 7);
#pragma unroll
            for (int jj = 0; jj < 2; ++jj) {
                unsigned v0 = tile[(cq << 1) + (jj << 5)][px2];
                unsigned v1 = tile[(cq << 1) + 1 + (jj << 5)][px2];
                *(uint2*)(orow + (cq << 2) + (jj << 6)) = make_uint2(v0, v1);
            }
        }
    } else if (bid < 1168) {
        int t = (bid - 1024) * 256 + tid;
        if (t < Cch * CK) {
            int oc = t / CK;
            int rem = t % CK;
            int k = rem >> 6, c = rem & 63;
            wbf[t] = f2bf(w[(oc * Cch + c) * 9 + k]);
        }
    } else {
        int t = (bid - 1168) * 256 + tid;
        if (t < 9 * 32 * 128) {
            int ci = t & 127, ocp = (t >> 7) & 31, tap = t >> 12;
            w9[t] = (ocp < NOFF) ? f2bf(wo[(ocp * 128 + ci) * 9 + tap]) : (unsigned short)0;
        }
    }
}

// ---------------------------------------------------------------------------
// Fused kernel, 4 waves. Block = (b, h, 16-px strip), XCD-swizzled blockIdx.
// A0 : stage tile3 from xtrc (coalesced, XOR-swizzled).
// A1 : offset MFMA; 4 waves = 2 oc-tiles x 2 ci-halves -> red (kh=1).
// FIN: kh==0 waves finalize offsets AND compute bilinear corner weights +
//      row byte-offsets once per (pixel,tap) -> wts/meta LDS (no offsL).
// B  : gather; thread=(px, c-quad); per tap: 2 LDS + 4 coalesced loads +
//      bilinear + cvt_pk; 2-tap rounds keep 8 loads in flight.
// B1 : deform MFMA; 18 per wave, direct store.
__global__ __launch_bounds__(256, 6) void fused_align(
        const unsigned short* __restrict__ xtrc,
        const unsigned short* __restrict__ w9,
        const unsigned short* __restrict__ wbf,
        const float* __restrict__ bias,
        float* __restrict__ out) {
    __shared__ union {
        unsigned short tile3[54 * 128];             // 13.5 KB
        unsigned short smp[16][CKPAD];              // 18.6 KB
    } u;
    __shared__ float red[2][64][4];                 // 2 KB
    __shared__ float4 wts[144];                     // 2.25 KB
    __shared__ int2 meta[144];                      // 1.1 KB

    int bi0 = blockIdx.x;
    int bi = ((bi0 & 7) << 9) | (bi0 >> 3);   // XCD-contiguous strips (4096%8==0)
    int b = bi >> 10;
    int rem = bi & 1023;
    int h = rem >> 3;
    int w0 = (rem & 7) << 4;
    int tid = threadIdx.x;
    int wv = tid >> 6, lane = tid & 63;
    int to = wv & 1;          // oc tile
    int kh = wv >> 1;         // ci half (0: x, 1: ref)
    int r16 = lane & 15;
    int g = lane >> 4;

    const unsigned short* xrow = xtrc + ((size_t)b << 21);   // b * 16384 * 128

    // bias preload for FIN waves (hides global latency behind A0/A1)
    float bias4[4] = {0.f, 0.f, 0.f, 0.f};
    if (kh == 0) {
#pragma unroll
        for (int r = 0; r < 4; ++r) {
            int oc = to * 16 + g * 4 + r;
            if (oc < NOFF) bias4[r] = bias[oc];
        }
    }

    // ---- Phase A0: stage 54 positions x 256B, fully coalesced ----
#pragma unroll
    for (int it = 0; it < 7; ++it) {
        int idx = it * 256 + tid;
        if (idx < 1728) {
            int lane32 = idx & 31;
            int pos = idx >> 5;              // row*18 + xx
            int row = pos / 18, xx = pos % 18;
            int yy = h + row - 1, xg = w0 + xx - 1;
            uint2 v = make_uint2(0u, 0u);
            if ((unsigned)yy < (unsigned)Hh && (unsigned)xg < (unsigned)Ww)
                v = *(const uint2*)(xrow + ((((yy << 7) + xg) << 7) + (lane32 << 2)));
            int ci0 = lane32 << 2;
            *(uint2*)(&u.tile3[(pos << 7) + (ci0 ^ ((xx & 7) << 3))]) = v;
        }
    }
    __syncthreads();

    // ---- Phase A1: offset conv MFMA (9 taps x 2 per wave) ----
    floatx4 acc = {0.f, 0.f, 0.f, 0.f};
#pragma unroll
    for (int tap = 0; tap < 9; ++tap) {
        int dy = tap / 3, dx = tap % 3;
        int xxr = r16 + dx;                              // 0..17
        const unsigned short* brow = &u.tile3[(dy * 18 + xxr) << 7];
        int sw = (xxr & 7) << 3;
        const unsigned short* arow = w9 + ((size_t)(tap * 32 + to * 16 + r16) << 7) + kh * 64;
#pragma unroll
        for (int kk = 0; kk < 2; ++kk) {
            int cb = kh * 64 + kk * 32 + g * 8;
            short8 bb = *(const short8*)(brow + (cb ^ sw));
            short8 a = *(const short8*)(arow + kk * 32 + g * 8);
            acc = __builtin_amdgcn_mfma_f32_16x16x32_bf16(a, bb, acc, 0, 0, 0);
        }
    }
    if (kh == 1) {
#pragma unroll
        for (int r = 0; r < 4; ++r) red[to][lane][r] = acc[r];
    }
    __syncthreads();

    // ---- FIN + META: kh==0 waves; thread (to,g,r16) owns oc = to*16+g*4+..,
    //      i.e. pixel p=r16, taps (to*8 + 2g) and +1 (to=1: only g==0 -> tap 8).
    if (kh == 0 && (to == 0 || g == 0)) {
        float vout[4];
#pragma unroll
        for (int r = 0; r < 4; ++r) {
            float v = acc[r] + red[to][lane][r] + bias4[r];
            vout[r] = fminf(fmaxf(v, -10.0f), 10.0f);
        }
        int ntap = (to == 0) ? 2 : 1;
        int kbase = (to * 16 + g * 4) >> 1;
        int p = r16;
#pragma unroll
        for (int t = 0; t < 2; ++t) {
            if (t < ntap) {
                int k = kbase + t;
                float dyo = vout[2 * t], dxo = vout[2 * t + 1];
                int ky = k / 3, kx = k % 3;
                float ys = (float)(h - 1 + ky) + dyo;
                float xs = (float)(w0 + p - 1 + kx) + dxo;
                float fy = floorf(ys), fx = floorf(xs);
                int iy0 = (int)fy, ix0 = (int)fx;
                float ty = ys - fy, tx = xs - fx;
                float wy0 = (1.f - ty) * (((unsigned)iy0 < (unsigned)Hh) ? 1.f : 0.f);
                float wy1 = ty         * (((unsigned)(iy0 + 1) < (unsigned)Hh) ? 1.f : 0.f);
                float wx0 = (1.f - tx) * (((unsigned)ix0 < (unsigned)Ww) ? 1.f : 0.f);
                float wx1 = tx         * (((unsigned)(ix0 + 1) < (unsigned)Ww) ? 1.f : 0.f);
                int ixb  = min(max(ix0, 0), Ww - 2);          // pair base [ixb, ixb+1]
                int iy0c = min(max(iy0, 0), Hh - 1);
                int iy1c = min(max(iy0 + 1, 0), Hh - 1);
                bool s0v = (min(max(ix0, 0), Ww - 1) != ixb);
                bool s1v = (min(max(ix0 + 1, 0), Ww - 1) != ixb);
                float w00 = wy0 * wx0, w01 = wy0 * wx1, w10 = wy1 * wx0, w11 = wy1 * wx1;
                float A  = (s0v ? 0.f : w00) + (s1v ? 0.f : w01);   // (y0, ixb)
                float Bw = (s0v ? w00 : 0.f) + (s1v ? w01 : 0.f);   // (y0, ixb+1)
                float Cw = (s0v ? 0.f : w10) + (s1v ? 0.f : w11);   // (y1, ixb)
                float Dw = (s0v ? w10 : 0.f) + (s1v ? w11 : 0.f);   // (y1, ixb+1)
                wts[p * 9 + k] = make_float4(A, Bw, Cw, Dw);
                // position byte offsets in xtrc (256B per position)
                meta[p * 9 + k] = make_int2(((iy0c << 7) + ixb) << 8,
                                            ((iy1c << 7) + ixb) << 8);
            }
        }
    }
    __syncthreads();   // wts/meta ready; tile3 dead -> smp may overwrite

    // ---- Phase B: bilinear gather; thread = (px, c-quad); 2-tap rounds ----
    {
        int p = tid >> 4, cq = tid & 15;
        const char* xb = (const char*)xrow + cq * 8;
        const float4* wp = &wts[p * 9];
        const int2* mp = &meta[p * 9];
#define GLOAD(k, q00, q01, q10, q11, wt, mm)                                          \
        float4 wt = wp[k]; int2 mm = mp[k];                                           \
        uint2 q00 = *(const uint2*)(xb + mm.x);                                       \
        uint2 q01 = *(const uint2*)(xb + mm.x + 256);                                 \
        uint2 q10 = *(const uint2*)(xb + mm.y);                                       \
        uint2 q11 = *(const uint2*)(xb + mm.y + 256);
#define BCOMP(k, q00, q01, q10, q11, wt) {                                            \
        float s0 = bflo(q00.x)*wt.x + bflo(q01.x)*wt.y + bflo(q10.x)*wt.z + bflo(q11.x)*wt.w; \
        float s1 = bfhi(q00.x)*wt.x + bfhi(q01.x)*wt.y + bfhi(q10.x)*wt.z + bfhi(q11.x)*wt.w; \
        float s2 = bflo(q00.y)*wt.x + bflo(q01.y)*wt.y + bflo(q10.y)*wt.z + bflo(q11.y)*wt.w; \
        float s3 = bfhi(q00.y)*wt.x + bfhi(q01.y)*wt.y + bfhi(q10.y)*wt.z + bfhi(q11.y)*wt.w; \
        *(uint2*)(&u.smp[p][(k) * 64 + cq * 4]) = make_uint2(cvtpk(s0, s1), cvtpk(s2, s3)); }
#pragma unroll
        for (int kp = 0; kp < 4; ++kp) {
            const int k0 = kp * 2, k1 = k0 + 1;
            GLOAD(k0, a00, a01, a10, a11, wtA, mmA)
            GLOAD(k1, b00, b01, b10, b11, wtB, mmB)
            BCOMP(k0, a00, a01, a10, a11, wtA)
            BCOMP(k1, b00, b01, b10, b11, wtB)
        }
        GLOAD(8, c00, c01, c10, c11, wtC, mmC)
        BCOMP(8, c00, c01, c10, c11, wtC)
#undef GLOAD
#undef BCOMP
    }
    __syncthreads();

    // ---- Phase B1: deform MFMA (18 per wave) + store ----
    floatx4 acc2 = {0.f, 0.f, 0.f, 0.f};
    const short8* ap = (const short8*)(wbf + (size_t)(wv * 16 + r16) * CK + g * 8);
    const unsigned short* bbase = &u.smp[r16][g * 8];
#pragma unroll
    for (int kk = 0; kk < 18; ++kk) {
        short8 a = ap[kk * 4];
        short8 bb = *(const short8*)(bbase + kk * 32);
        acc2 = __builtin_amdgcn_mfma_f32_16x16x32_bf16(a, bb, acc2, 0, 0, 0);
    }
    size_t obase = ((size_t)(b * Cch + wv * 16 + g * 4)) << 14;
    int hw = (h << 7) + w0 + r16;
#pragma unroll
    for (int r = 0; r < 4; ++r)
        out[obase + ((size_t)r << 14) + hw] = acc2[r];
}

// ---------------------------------------------------------------------------
extern "C" void kernel_launch(void* const* d_in, const int* in_sizes, int n_in,
                              void* d_out, int out_size, void* d_ws, size_t ws_size,
                              hipStream_t stream) {
    const float* x      = (const float*)d_in[0];
    const float* ref    = (const float*)d_in[1];
    const float* wo     = (const float*)d_in[2];
    const float* bias   = (const float*)d_in[3];
    const float* weight = (const float*)d_in[4];
    float* out = (float*)d_out;

    unsigned short* w9   = (unsigned short*)d_ws;                      // 72 KB
    unsigned short* wbf  = (unsigned short*)((char*)d_ws + 131072);    // 72 KB
    unsigned short* xtrc = (unsigned short*)((char*)d_ws + 262144);    // 16.78 MB

    hipLaunchKernelGGL(prep, dim3(1312), dim3(256), 0, stream,
                       x, ref, wo, weight, xtrc, w9, wbf);
    hipLaunchKernelGGL(fused_align, dim3(Bsz * Hh * (Ww / 16)), dim3(256), 0, stream,
                       xtrc, w9, wbf, bias, out);
}

// Round 13
// 78.012 us; speedup vs baseline: 1.3189x; 1.2866x over previous
//
#include <hip/hip_runtime.h>

#define Bsz 4
#define Cch 64
#define Hh 128
#define Ww 128
#define NOFF 18      // 2*3*3 offset channels
#define CK 576       // 64*9 reduction length for deform einsum (K = k*64 + c)
#define CKPAD 580    // smp row stride (bf16): 1160B

typedef __attribute__((ext_vector_type(8))) short short8;
typedef __attribute__((ext_vector_type(4))) float floatx4;

__device__ __forceinline__ unsigned short f2bf(float f) {
    union { float f; unsigned u; } v; v.f = f;
    unsigned r = v.u + 0x7fff + ((v.u >> 16) & 1);   // round-to-nearest-even
    return (unsigned short)(r >> 16);
}
__device__ __forceinline__ float bflo(unsigned d) {
    union { unsigned u; float f; } v; v.u = d << 16; return v.f;
}
__device__ __forceinline__ float bfhi(unsigned d) {
    union { unsigned u; float f; } v; v.u = d & 0xffff0000u; return v.f;
}
__device__ __forceinline__ unsigned cvtpk(float lo, float hi) {   // {bf16(lo), bf16(hi)<<16}
    unsigned r;
    asm("v_cvt_pk_bf16_f32 %0, %1, %2" : "=v"(r) : "v"(lo), "v"(hi));
    return r;
}

// ---------------------------------------------------------------------------
// Prep kernel.
//   blocks 0..511  : build xpair[b][h*w][128ch] u32 = {bf16 v(pos,c), bf16 v(pos+1,c)}
//                    (pos+1 clamped within row; hi of last col never used by gather)
//   blocks 512..655: deform weight w[oc][c][tap] -> wbf[oc][tap*64+c] bf16
//   blocks 656..799: offset weight wo[oc][ci][tap] -> w9[tap][32ocp][128ci] bf16
__global__ __launch_bounds__(256) void prep(const float* __restrict__ x,
                                            const float* __restrict__ ref,
                                            const float* __restrict__ wo,
                                            const float* __restrict__ w,
                                            unsigned* __restrict__ xpair,
                                            unsigned short* __restrict__ w9,
                                            unsigned short* __restrict__ wbf) {
    __shared__ unsigned tile[64][130];   // [cpair][px]; stride 130 u32
    int bid = blockIdx.x;
    int tid = threadIdx.x;
    if (bid < 512) {
        int b = bid >> 7;
        int h = bid & 127;
        int px2 = tid & 63;              // pixel pair: px = 2*px2, 2*px2+1
        int cg = tid >> 6;               // 32-channel group
        const float* xb = x + ((size_t)b << 20) + (h << 7) + (px2 << 1);
        const float* rb = ref + ((size_t)b << 20) + (h << 7) + (px2 << 1);
#pragma unroll
        for (int j = 0; j < 16; ++j) {
            int c0 = cg * 32 + 2 * j;
            const float* s = (c0 < 64) ? xb : rb;
            int cl = c0 & 63;
            float2 va = *(const float2*)(s + ((size_t)cl << 14));
            float2 vb = *(const float2*)(s + ((size_t)(cl + 1) << 14));
            unsigned w0 = (unsigned)f2bf(va.x) | ((unsigned)f2bf(vb.x) << 16);
            unsigned w1 = (unsigned)f2bf(va.y) | ((unsigned)f2bf(vb.y) << 16);
            *(uint2*)(&tile[c0 >> 1][px2 << 1]) = make_uint2(w0, w1);
        }
        __syncthreads();
#pragma unroll
        for (int it = 0; it < 16; ++it) {
            int idx = it * 256 + tid;
            int cq5 = idx & 31;          // 4-channel group
            int pos = idx >> 5;          // 0..127
            int posn = min(pos + 1, 127);
            unsigned t0 = tile[2 * cq5][pos], t0n = tile[2 * cq5][posn];
            unsigned t1 = tile[2 * cq5 + 1][pos], t1n = tile[2 * cq5 + 1][posn];
            uint4 o;
            o.x = (t0 & 0xffffu) | (t0n << 16);
            o.y = (t0 >> 16) | (t0n & 0xffff0000u);
            o.z = (t1 & 0xffffu) | (t1n << 16);
            o.w = (t1 >> 16) | (t1n & 0xffff0000u);
            *(uint4*)(xpair + (((size_t)(b << 14) + (h << 7) + pos) << 7) + (cq5 << 2)) = o;
        }
    } else if (bid < 656) {
        int t = (bid - 512) * 256 + tid;
        if (t < Cch * CK) {
            int oc = t / CK;
            int rem = t % CK;
            int k = rem >> 6, c = rem & 63;
            wbf[t] = f2bf(w[(oc * Cch + c) * 9 + k]);
        }
    } else {
        int t = (bid - 656) * 256 + tid;
        if (t < 9 * 32 * 128) {
            int ci = t & 127, ocp = (t >> 7) & 31, tap = t >> 12;
            w9[t] = (ocp < NOFF) ? f2bf(wo[(ocp * 128 + ci) * 9 + tap]) : (unsigned short)0;
        }
    }
}

// ---------------------------------------------------------------------------
// Fused kernel, 32-px blocks (2 sub-strips). Block = (b, h, 32-px strip).
// A0 : stage tile3[3][34][128] bf16 from xpair lows (coalesced, XOR-swizzled).
// A1 : offset MFMA; wave (to,kh) runs BOTH sub-strips reusing w9 fragments.
// FIN: kh==0 waves finalize offsets + corner weights/meta for both strips.
// B  : gather from xpair: per tap ONE uint4 per row (both x-corners packed).
// B1 : deform MFMA; wave = oc-tile, both sub-strips reuse wbf fragments.
__global__ __launch_bounds__(256, 3) void fused_align(
        const unsigned* __restrict__ xpair,
        const unsigned short* __restrict__ w9,
        const unsigned short* __restrict__ wbf,
        const float* __restrict__ bias,
        float* __restrict__ out) {
    __shared__ union {
        unsigned short tile3[3 * 34 * 128];         // 26.1 KB
        unsigned short smp[32][CKPAD];              // 37.1 KB
    } u;
    __shared__ float red[2][2][64][4];              // [strip][to] 4 KB
    __shared__ float4 wts[288];                     // 4.6 KB
    __shared__ int2 meta[288];                      // 2.3 KB

    int bi0 = blockIdx.x;
    int bi = ((bi0 & 7) << 8) | (bi0 >> 3);   // XCD swizzle (2048 = 8*256)
    int b = bi >> 9;
    int rem = bi & 511;
    int h = rem >> 2;
    int w0 = (rem & 3) << 5;
    int tid = threadIdx.x;
    int wv = tid >> 6, lane = tid & 63;
    int to = wv & 1;          // oc tile (offset conv)
    int kh = wv >> 1;         // ci half (0: x, 1: ref)
    int r16 = lane & 15;
    int g = lane >> 4;

    const unsigned* xp32 = xpair + ((size_t)b << 21);   // b * 16384 pos * 128 u32

    float bias4[4] = {0.f, 0.f, 0.f, 0.f};
    if (kh == 0) {
#pragma unroll
        for (int r = 0; r < 4; ++r) {
            int oc = to * 16 + g * 4 + r;
            if (oc < NOFF) bias4[r] = bias[oc];
        }
    }

    // ---- Phase A0: stage 102 positions x 256B from xpair lows ----
#pragma unroll
    for (int it = 0; it < 13; ++it) {
        int idx = it * 256 + tid;
        if (idx < 3264) {
            int cq4 = idx & 31;              // 4-channel group
            int pos = idx >> 5;              // row*34 + xx
            int row = pos / 34, xx = pos % 34;
            int yy = h + row - 1, xg = w0 + xx - 1;
            uint4 q = make_uint4(0u, 0u, 0u, 0u);
            if ((unsigned)yy < (unsigned)Hh && (unsigned)xg < (unsigned)Ww)
                q = *(const uint4*)(xp32 + (((yy << 7) + xg) << 7) + (cq4 << 2));
            unsigned p0 = (q.x & 0xffffu) | (q.y << 16);
            unsigned p1 = (q.z & 0xffffu) | (q.w << 16);
            int ci0 = cq4 << 2;
            *(uint2*)(&u.tile3[(pos << 7) + (ci0 ^ ((xx & 7) << 3))]) = make_uint2(p0, p1);
        }
    }
    __syncthreads();

    // ---- Phase A1: offset conv MFMA; both strips share w9 fragments ----
    floatx4 accA0 = {0.f, 0.f, 0.f, 0.f};
    floatx4 accA1 = {0.f, 0.f, 0.f, 0.f};
#pragma unroll
    for (int tap = 0; tap < 9; ++tap) {
        int dy = tap / 3, dx = tap % 3;
        const unsigned short* arow = w9 + ((size_t)(tap * 32 + to * 16 + r16) << 7) + kh * 64;
        short8 a0 = *(const short8*)(arow + g * 8);          // k-group g, kk=0
        short8 a1 = *(const short8*)(arow + 32 + g * 8);     // k-group g, kk=1
#pragma unroll
        for (int s = 0; s < 2; ++s) {
            int xxr = r16 + dx + s * 16;                     // 0..33
            const unsigned short* brow = &u.tile3[(dy * 34 + xxr) << 7];
            int sw = (xxr & 7) << 3;
            int cb0 = kh * 64 + g * 8;
            short8 bb0 = *(const short8*)(brow + (cb0 ^ sw));
            short8 bb1 = *(const short8*)(brow + ((cb0 + 32) ^ sw));
            if (s == 0) {
                accA0 = __builtin_amdgcn_mfma_f32_16x16x32_bf16(a0, bb0, accA0, 0, 0, 0);
                accA0 = __builtin_amdgcn_mfma_f32_16x16x32_bf16(a1, bb1, accA0, 0, 0, 0);
            } else {
                accA1 = __builtin_amdgcn_mfma_f32_16x16x32_bf16(a0, bb0, accA1, 0, 0, 0);
                accA1 = __builtin_amdgcn_mfma_f32_16x16x32_bf16(a1, bb1, accA1, 0, 0, 0);
            }
        }
    }
    if (kh == 1) {
#pragma unroll
        for (int r = 0; r < 4; ++r) { red[0][to][lane][r] = accA0[r]; red[1][to][lane][r] = accA1[r]; }
    }
    __syncthreads();

    // ---- FIN: offsets -> corner weights + row byte-offsets, both strips ----
    if (kh == 0 && (to == 0 || g == 0)) {
        int ntap = (to == 0) ? 2 : 1;
        int kbase = (to * 16 + g * 4) >> 1;
#pragma unroll
        for (int s = 0; s < 2; ++s) {
            float vout[4];
#pragma unroll
            for (int r = 0; r < 4; ++r) {
                float v = (s == 0 ? accA0[r] : accA1[r]) + red[s][to][lane][r] + bias4[r];
                vout[r] = fminf(fmaxf(v, -10.0f), 10.0f);
            }
            int p = s * 16 + r16;
#pragma unroll
            for (int t = 0; t < 2; ++t) {
                if (t < ntap) {
                    int k = kbase + t;
                    float dyo = vout[2 * t], dxo = vout[2 * t + 1];
                    int ky = k / 3, kx = k % 3;
                    float ys = (float)(h - 1 + ky) + dyo;
                    float xs = (float)(w0 + p - 1 + kx) + dxo;
                    float fy = floorf(ys), fx = floorf(xs);
                    int iy0 = (int)fy, ix0 = (int)fx;
                    float ty = ys - fy, tx = xs - fx;
                    float wy0 = (1.f - ty) * (((unsigned)iy0 < (unsigned)Hh) ? 1.f : 0.f);
                    float wy1 = ty         * (((unsigned)(iy0 + 1) < (unsigned)Hh) ? 1.f : 0.f);
                    float wx0 = (1.f - tx) * (((unsigned)ix0 < (unsigned)Ww) ? 1.f : 0.f);
                    float wx1 = tx         * (((unsigned)(ix0 + 1) < (unsigned)Ww) ? 1.f : 0.f);
                    int ixb  = min(max(ix0, 0), Ww - 2);
                    int iy0c = min(max(iy0, 0), Hh - 1);
                    int iy1c = min(max(iy0 + 1, 0), Hh - 1);
                    bool s0v = (min(max(ix0, 0), Ww - 1) != ixb);
                    bool s1v = (min(max(ix0 + 1, 0), Ww - 1) != ixb);
                    float w00 = wy0 * wx0, w01 = wy0 * wx1, w10 = wy1 * wx0, w11 = wy1 * wx1;
                    float A  = (s0v ? 0.f : w00) + (s1v ? 0.f : w01);   // (y0, ixb)
                    float Bw = (s0v ? w00 : 0.f) + (s1v ? w01 : 0.f);   // (y0, ixb+1)
                    float Cw = (s0v ? 0.f : w10) + (s1v ? 0.f : w11);   // (y1, ixb)
                    float Dw = (s0v ? w10 : 0.f) + (s1v ? w11 : 0.f);   // (y1, ixb+1)
                    wts[p * 9 + k] = make_float4(A, Bw, Cw, Dw);
                    meta[p * 9 + k] = make_int2(((iy0c << 7) + ixb) << 9,
                                                ((iy1c << 7) + ixb) << 9);
                }
            }
        }
    }
    __syncthreads();   // wts/meta ready; tile3 dead -> smp may overwrite

    // ---- Phase B: gather; thread = (p0, cq) handles px p0 and p0+16 ----
    {
        int p0 = tid >> 4, cq = tid & 15;
        const char* xbB = (const char*)xpair + ((size_t)b << 23) + cq * 16;
#define GL(k, p, q0, q1, wt, mm)                                                      \
        float4 wt = wts[(p) * 9 + (k)]; int2 mm = meta[(p) * 9 + (k)];                \
        uint4 q0 = *(const uint4*)(xbB + mm.x);                                       \
        uint4 q1 = *(const uint4*)(xbB + mm.y);
#define CP(k, p, q0, q1, wt) {                                                        \
        float s0 = bflo(q0.x)*wt.x + bfhi(q0.x)*wt.y + bflo(q1.x)*wt.z + bfhi(q1.x)*wt.w; \
        float s1 = bflo(q0.y)*wt.x + bfhi(q0.y)*wt.y + bflo(q1.y)*wt.z + bfhi(q1.y)*wt.w; \
        float s2 = bflo(q0.z)*wt.x + bfhi(q0.z)*wt.y + bflo(q1.z)*wt.z + bfhi(q1.z)*wt.w; \
        float s3 = bflo(q0.w)*wt.x + bfhi(q0.w)*wt.y + bflo(q1.w)*wt.z + bfhi(q1.w)*wt.w; \
        *(uint2*)(&u.smp[p][(k) * 64 + cq * 4]) = make_uint2(cvtpk(s0, s1), cvtpk(s2, s3)); }
#pragma unroll
        for (int s = 0; s < 2; ++s) {
            int p = p0 + s * 16;
            GL(0, p, a0, a1, wA, mA)
            GL(1, p, b0, b1, wB, mB)
            GL(2, p, c0, c1, wC, mC)
            CP(0, p, a0, a1, wA)
            CP(1, p, b0, b1, wB)
            CP(2, p, c0, c1, wC)
            GL(3, p, d0, d1, wD, mD)
            GL(4, p, e0, e1, wE, mE)
            GL(5, p, f0, f1, wF, mF)
            CP(3, p, d0, d1, wD)
            CP(4, p, e0, e1, wE)
            CP(5, p, f0, f1, wF)
            GL(6, p, g0, g1, wG, mG)
            GL(7, p, h0, h1, wH, mH)
            GL(8, p, i0, i1, wI, mI)
            CP(6, p, g0, g1, wG)
            CP(7, p, h0, h1, wH)
            CP(8, p, i0, i1, wI)
        }
#undef GL
#undef CP
    }
    __syncthreads();

    // ---- Phase B1: deform MFMA; both strips share wbf fragments ----
    {
        floatx4 acc0 = {0.f, 0.f, 0.f, 0.f};
        floatx4 acc1 = {0.f, 0.f, 0.f, 0.f};
        const short8* ap = (const short8*)(wbf + (size_t)(wv * 16 + r16) * CK + g * 8);
        const unsigned short* bb0 = &u.smp[r16][g * 8];
        const unsigned short* bb1 = &u.smp[16 + r16][g * 8];
#pragma unroll
        for (int kk = 0; kk < 18; ++kk) {
            short8 a = ap[kk * 4];
            short8 v0 = *(const short8*)(bb0 + kk * 32);
            short8 v1 = *(const short8*)(bb1 + kk * 32);
            acc0 = __builtin_amdgcn_mfma_f32_16x16x32_bf16(a, v0, acc0, 0, 0, 0);
            acc1 = __builtin_amdgcn_mfma_f32_16x16x32_bf16(a, v1, acc1, 0, 0, 0);
        }
        size_t obase = ((size_t)(b * Cch + wv * 16 + g * 4)) << 14;
        int hw = (h << 7) + w0 + r16;
#pragma unroll
        for (int r = 0; r < 4; ++r) {
            out[obase + ((size_t)r << 14) + hw] = acc0[r];
            out[obase + ((size_t)r << 14) + hw + 16] = acc1[r];
        }
    }
}

// ---------------------------------------------------------------------------
extern "C" void kernel_launch(void* const* d_in, const int* in_sizes, int n_in,
                              void* d_out, int out_size, void* d_ws, size_t ws_size,
                              hipStream_t stream) {
    const float* x      = (const float*)d_in[0];
    const float* ref    = (const float*)d_in[1];
    const float* wo     = (const float*)d_in[2];
    const float* bias   = (const float*)d_in[3];
    const float* weight = (const float*)d_in[4];
    float* out = (float*)d_out;

    unsigned short* w9  = (unsigned short*)d_ws;                      // 72 KB
    unsigned short* wbf = (unsigned short*)((char*)d_ws + 262144);    // 72 KB
    unsigned* xpair     = (unsigned*)((char*)d_ws + 524288);          // 33.5 MB

    hipLaunchKernelGGL(prep, dim3(800), dim3(256), 0, stream,
                       x, ref, wo, weight, xpair, w9, wbf);
    hipLaunchKernelGGL(fused_align, dim3(2048), dim3(256), 0, stream,
                       xpair, w9, wbf, bias, out);
}